// Round 6
// baseline (417.009 us; speedup 1.0000x reference)
//
#include <hip/hip_runtime.h>
#include <hip/hip_bf16.h>

typedef __attribute__((ext_vector_type(8))) short short8;
typedef __attribute__((ext_vector_type(4))) float f32x4;

#define GL2LDS16(g, l)                                                         \
  __builtin_amdgcn_global_load_lds(                                            \
      (const __attribute__((address_space(1))) unsigned int*)(g),              \
      (__attribute__((address_space(3))) unsigned int*)(l), 16, 0, 0)

// Inline-asm ds_read_b128: invisible to the compiler's waitcnt pass, so our
// counted s_waitcnt vmcnt(N) is not followed by a compiler-inserted vmcnt(0)
// drain for outstanding LDS-DMA ops. lgkmcnt handled manually (rule #18).
__device__ __forceinline__ short8 lds_read_b128(const __hip_bfloat16* p) {
  short8 v;
  asm volatile("ds_read_b128 %0, %1"
               : "=v"(v)
               : "v"((unsigned)(uintptr_t)p));
  return v;
}

// ---------------------------------------------------------------------------
// feat[row][0:1024] = x_m[m_ids[row]]; feat[row][1024:2048] = x_op[op_idx[row]]
// (bf16). Also srow[row] = job_srpt[job_ids[row]] (fp32).
// ---------------------------------------------------------------------------
__global__ __launch_bounds__(256) void feat_kernel(
    const float* __restrict__ x_m, const float* __restrict__ x_op,
    const float* __restrict__ job_srpt, const int* __restrict__ m_ids,
    const int* __restrict__ op_idx, const int* __restrict__ job_ids,
    __hip_bfloat16* __restrict__ feat, float* __restrict__ srow) {
  const int row = blockIdx.x;
  const int t = threadIdx.x;
  const int j0 = t * 8;
  const float* src;
  if (j0 < 1024)
    src = x_m + (long)m_ids[row] * 1024 + j0;
  else
    src = x_op + (long)op_idx[row] * 1024 + (j0 - 1024);
  float4 v0 = *(const float4*)src;
  float4 v1 = *(const float4*)(src + 4);
  union {
    __hip_bfloat16 h[8];
    int4 i4;
  } u;
  u.h[0] = __float2bfloat16(v0.x);
  u.h[1] = __float2bfloat16(v0.y);
  u.h[2] = __float2bfloat16(v0.z);
  u.h[3] = __float2bfloat16(v0.w);
  u.h[4] = __float2bfloat16(v1.x);
  u.h[5] = __float2bfloat16(v1.y);
  u.h[6] = __float2bfloat16(v1.z);
  u.h[7] = __float2bfloat16(v1.w);
  *(int4*)&feat[(long)row * 2048 + j0] = u.i4;
  if (t == 0) srow[row] = job_srpt[job_ids[row]];
}

// ---------------------------------------------------------------------------
// Transpose-convert fp32 W[K][1024] -> bf16 Wt[1024][K].
// ---------------------------------------------------------------------------
__global__ __launch_bounds__(256) void wconv_kernel(
    const float* __restrict__ W, __hip_bfloat16* __restrict__ Wt, int K) {
  __shared__ float tile[64][65];
  const int kb = blockIdx.x * 64;
  const int nb = blockIdx.y * 64;
  const int t = threadIdx.x;
#pragma unroll
  for (int it = 0; it < 16; ++it) {
    int idx = it * 256 + t;
    int kk = idx >> 6, nn = idx & 63;
    tile[kk][nn] = W[(long)(kb + kk) * 1024 + nb + nn];
  }
  __syncthreads();
#pragma unroll
  for (int it = 0; it < 16; ++it) {
    int idx = it * 256 + t;
    int nn = idx >> 6, kk = idx & 63;
    Wt[(long)(nb + nn) * K + kb + kk] = __float2bfloat16(tile[kk][nn]);
  }
}

// ---------------------------------------------------------------------------
// C[M][N] = lrelu(A[M][K] @ Bt[N][K]^T + bias (+ rank2 srpt/pt correction))
// 256x256 tile, BK=64, 8 waves (2Mx4N), double-buffered LDS, 8-phase
// schedule, counted vmcnt(4), raw s_barrier, inline-asm ds_read_b128 +
// manual lgkmcnt(0) + sched_barrier(0). LDS 16B-chunk XOR swizzle both-sides.
// GRID IS (N/256, M/256): blockIdx.x = COLUMN tile. With round-robin
// workgroup->XCD assignment (xcd = bid%8) and gridDim.x=4, each XCD serves a
// single B column-panel (1MB, L2-resident) -> kills the B L2-thrash that
// capped GEMM0 at 5.1 TB/s tile supply.
// ---------------------------------------------------------------------------
__global__ __launch_bounds__(512, 2) void gemm_kernel(
    const __hip_bfloat16* __restrict__ A, const __hip_bfloat16* __restrict__ Bt,
    __hip_bfloat16* __restrict__ C, const float* __restrict__ bias, int M,
    int N, int K, int rank2, const float* __restrict__ wr0,
    const float* __restrict__ wr1, const float* __restrict__ srow,
    const float* __restrict__ ptv, int fuseW3,
    const float* __restrict__ W3, float* __restrict__ scoreOut) {
  __shared__ __align__(16) __hip_bfloat16 As[2][256 * 64];
  __shared__ __align__(16) __hip_bfloat16 Bs[2][256 * 64];
  const int t = threadIdx.x;
  const int lane = t & 63;
  const int wid = t >> 6;   // 0..7
  const int wm = wid >> 2;  // 0..1  (M half: 128 rows)
  const int wn = wid & 3;   // 0..3  (N quarter: 64 cols)
  const long arow0 = (long)blockIdx.y * 256;   // row tile (slow axis)
  const int bcol0 = blockIdx.x * 256;          // col tile (fast axis -> XCD)
  const int NT = K >> 6;

  // staging geometry (1 load/thread per 8KB chunk, LDS dest linear in t)
  const int sa_row = ((t >> 8) * 128) + ((t >> 3) & 31);  // + p*32
  const int sb_row = t >> 3;                              // + q*64
  const int scol = ((t & 7) ^ ((t >> 3) & 7)) * 8;        // pre-swizzled col

#define STAGE_A(buf, kt1, p)                                                   \
  GL2LDS16(A + (arow0 + sa_row + (p) * 32) * (long)K + (kt1) * 64 + scol,      \
           &As[buf][(t >> 8) * 8192 + (p) * 2048 + (t & 255) * 8])
#define STAGE_B(buf, kt1, q)                                                   \
  GL2LDS16(Bt + (long)(bcol0 + sb_row + (q) * 64) * (long)K + (kt1) * 64 + scol, \
           &Bs[buf][(q) * 4096 + t * 8])

  f32x4 acc[8][4] = {};
  short8 bfr[8];

  // prologue: stage all of tile 0 (order matches steady state: B0..B3,A0..A3)
#pragma unroll
  for (int q = 0; q < 4; ++q) STAGE_B(0, 0, q);
#pragma unroll
  for (int p = 0; p < 4; ++p) STAGE_A(0, 0, p);

  for (int kt = 0; kt < NT; ++kt) {
    const int cur = kt & 1;
    const bool pre = (kt + 1) < NT;
#pragma unroll
    for (int p = 0; p < 4; ++p) {
      if (pre) {
        if (p == 0) { STAGE_B(cur ^ 1, kt + 1, 0); STAGE_B(cur ^ 1, kt + 1, 1); }
        if (p == 1) { STAGE_B(cur ^ 1, kt + 1, 2); STAGE_B(cur ^ 1, kt + 1, 3); }
        if (p == 2) { STAGE_A(cur ^ 1, kt + 1, 0); STAGE_A(cur ^ 1, kt + 1, 1); }
        if (p == 3) { STAGE_A(cur ^ 1, kt + 1, 2); STAGE_A(cur ^ 1, kt + 1, 3); }
        asm volatile("s_waitcnt vmcnt(4)" ::: "memory");
      } else {
        asm volatile("s_waitcnt vmcnt(0)" ::: "memory");
      }
      __builtin_amdgcn_s_barrier();

      short8 af[2][2];
      if (p == 0) {
#pragma unroll
        for (int j = 0; j < 4; ++j)
#pragma unroll
          for (int ks = 0; ks < 2; ++ks) {
            const int ko = (ks * 32 + ((lane >> 4) << 3)) ^ ((lane & 7) << 3);
            bfr[j * 2 + ks] =
                lds_read_b128(&Bs[cur][(wn * 64 + j * 16 + (lane & 15)) * 64 + ko]);
          }
      }
#pragma unroll
      for (int ii = 0; ii < 2; ++ii)
#pragma unroll
        for (int ks = 0; ks < 2; ++ks) {
          const int ko = (ks * 32 + ((lane >> 4) << 3)) ^ ((lane & 7) << 3);
          af[ii][ks] = lds_read_b128(
              &As[cur][(wm * 128 + (2 * p + ii) * 16 + (lane & 15)) * 64 + ko]);
        }

      asm volatile("s_waitcnt lgkmcnt(0)" ::: "memory");
      __builtin_amdgcn_sched_barrier(0);  // rule #18: pin MFMAs below the wait
      __builtin_amdgcn_s_setprio(1);
#pragma unroll
      for (int ii = 0; ii < 2; ++ii)
#pragma unroll
        for (int ks = 0; ks < 2; ++ks)
#pragma unroll
          for (int j = 0; j < 4; ++j)
            acc[2 * p + ii][j] = __builtin_amdgcn_mfma_f32_16x16x32_bf16(
                af[ii][ks], bfr[j * 2 + ks], acc[2 * p + ii][j], 0, 0, 0);
      __builtin_amdgcn_s_setprio(0);
      __builtin_amdgcn_s_barrier();
    }
  }

  if (!fuseW3) {
#pragma unroll
    for (int j = 0; j < 4; ++j) {
      const int c = bcol0 + wn * 64 + j * 16 + (lane & 15);
      const float bia = bias[c];
      float wa = 0.f, wb = 0.f;
      if (rank2) {
        wa = wr0[c];
        wb = wr1[c];
      }
#pragma unroll
      for (int i = 0; i < 8; ++i) {
        const long rb = arow0 + wm * 128 + i * 16 + ((lane >> 4) << 2);
#pragma unroll
        for (int g = 0; g < 4; ++g) {
          const long r = rb + g;
          float v = acc[i][j][g] + bia;
          if (rank2) v += srow[r] * wa + ptv[r] * wb;
          v = v > 0.f ? v : 0.01f * v;
          C[r * N + c] = __float2bfloat16(v);
        }
      }
    }
  } else {
    float bia[4], w3v[4];
#pragma unroll
    for (int j = 0; j < 4; ++j) {
      const int c = bcol0 + wn * 64 + j * 16 + (lane & 15);
      bia[j] = bias[c];
      w3v[j] = W3[c];
    }
#pragma unroll
    for (int i = 0; i < 8; ++i) {
#pragma unroll
      for (int g = 0; g < 4; ++g) {
        float ps = 0.f;
#pragma unroll
        for (int j = 0; j < 4; ++j) {
          float v = acc[i][j][g] + bia[j];
          v = v > 0.f ? v : 0.01f * v;
          ps += v * w3v[j];
        }
        ps += __shfl_xor(ps, 1);
        ps += __shfl_xor(ps, 2);
        ps += __shfl_xor(ps, 4);
        ps += __shfl_xor(ps, 8);
        if ((lane & 15) == 0) {
          const long r = arow0 + wm * 128 + i * 16 + ((lane >> 4) << 2) + g;
          atomicAdd(&scoreOut[r], ps);
        }
      }
    }
  }
#undef STAGE_A
#undef STAGE_B
}

// ---------------------------------------------------------------------------
// softmax + argmax reductions (b3 is a constant shift -> cancels in softmax
// and does not change argmax; omitted).
// ---------------------------------------------------------------------------
__global__ __launch_bounds__(256) void redmax_kernel(
    const float* __restrict__ score, float* __restrict__ pmax,
    int* __restrict__ pidx) {
  const int t = threadIdx.x, b = blockIdx.x;
  float m = -1e30f;
  int mi = 0;
#pragma unroll
  for (int u = 0; u < 2; ++u) {
    int i = b * 512 + u * 256 + t;
    float v = score[i];
    if (v > m) {
      m = v;
      mi = i;
    }
  }
  __shared__ float sm[4];
  __shared__ int si[4];
#pragma unroll
  for (int off = 32; off; off >>= 1) {
    float om = __shfl_down(m, off);
    int oi = __shfl_down(mi, off);
    if (om > m || (om == m && oi < mi)) {
      m = om;
      mi = oi;
    }
  }
  const int lane = t & 63, w = t >> 6;
  if (lane == 0) {
    sm[w] = m;
    si[w] = mi;
  }
  __syncthreads();
  if (t == 0) {
    for (int w2 = 1; w2 < 4; ++w2)
      if (sm[w2] > m || (sm[w2] == m && si[w2] < mi)) {
        m = sm[w2];
        mi = si[w2];
      }
    pmax[b] = m;
    pidx[b] = mi;
  }
}

__global__ __launch_bounds__(64) void finmax_kernel(
    const float* __restrict__ pmax, const int* __restrict__ pidx,
    float* __restrict__ gscal, float* __restrict__ out_idx) {
  const int t = threadIdx.x;
  float m = pmax[t];
  int mi = pidx[t];
#pragma unroll
  for (int off = 32; off; off >>= 1) {
    float om = __shfl_down(m, off);
    int oi = __shfl_down(mi, off);
    if (om > m || (om == m && oi < mi)) {
      m = om;
      mi = oi;
    }
  }
  if (t == 0) {
    gscal[0] = m;
    out_idx[0] = (float)mi;
  }
}

__global__ __launch_bounds__(256) void expsum_kernel(
    const float* __restrict__ score, const float* __restrict__ gscal,
    float* __restrict__ e, float* __restrict__ psum) {
  const int t = threadIdx.x, b = blockIdx.x;
  const float gmax = gscal[0];
  float s = 0.f;
#pragma unroll
  for (int u = 0; u < 2; ++u) {
    int i = b * 512 + u * 256 + t;
    float v = expf(score[i] - gmax);
    e[i] = v;
    s += v;
  }
#pragma unroll
  for (int off = 32; off; off >>= 1) s += __shfl_down(s, off);
  __shared__ float sm[4];
  const int lane = t & 63, w = t >> 6;
  if (lane == 0) sm[w] = s;
  __syncthreads();
  if (t == 0) psum[b] = sm[0] + sm[1] + sm[2] + sm[3];
}

__global__ __launch_bounds__(64) void finsum_kernel(const float* __restrict__ psum,
                                                    float* __restrict__ gscal) {
  float s = psum[threadIdx.x];
#pragma unroll
  for (int off = 32; off; off >>= 1) s += __shfl_down(s, off);
  if (threadIdx.x == 0) gscal[1] = 1.0f / s;
}

__global__ __launch_bounds__(256) void scale_kernel(float* __restrict__ e,
                                                    const float* __restrict__ gscal) {
  const float inv = gscal[1];
  const int i = blockIdx.x * 512 + threadIdx.x;
  e[i] *= inv;
  e[i + 256] *= inv;
}

// ---------------------------------------------------------------------------
extern "C" void kernel_launch(void* const* d_in, const int* in_sizes, int n_in,
                              void* d_out, int out_size, void* d_ws,
                              size_t ws_size, hipStream_t stream) {
  const float* x_m = (const float*)d_in[0];
  const float* x_op = (const float*)d_in[1];
  const float* job_srpt = (const float*)d_in[2];
  const float* pt = (const float*)d_in[3];
  const float* W0 = (const float*)d_in[4];
  const float* b0 = (const float*)d_in[5];
  const float* W1 = (const float*)d_in[6];
  const float* b1 = (const float*)d_in[7];
  const float* W2 = (const float*)d_in[8];
  const float* b2 = (const float*)d_in[9];
  const float* W3 = (const float*)d_in[10];
  const int* m_ids = (const int*)d_in[12];
  const int* op_idx = (const int*)d_in[13];
  const int* job_ids = (const int*)d_in[14];

  const int M = 32768;

  char* p = (char*)d_ws;
  __hip_bfloat16* feat = (__hip_bfloat16*)p;            p += (size_t)M * 2048 * 2;
  __hip_bfloat16* hA = (__hip_bfloat16*)p;              p += (size_t)M * 1024 * 2;
  __hip_bfloat16* hB = (__hip_bfloat16*)p;              p += (size_t)M * 1024 * 2;
  __hip_bfloat16* Wt0 = (__hip_bfloat16*)p;             p += (size_t)1024 * 2048 * 2;
  __hip_bfloat16* Wt1 = (__hip_bfloat16*)p;             p += (size_t)1024 * 1024 * 2;
  __hip_bfloat16* Wt2 = (__hip_bfloat16*)p;             p += (size_t)1024 * 1024 * 2;
  float* srow = (float*)p;                              p += (size_t)M * 4;
  float* score = (float*)p;                             p += (size_t)M * 4;
  float* pmax = (float*)p;                              p += 256;
  int* pidx = (int*)p;                                  p += 256;
  float* psum = (float*)p;                              p += 256;
  float* gscal = (float*)p;                             p += 256;

  float* probs = (float*)d_out;
  float* out_idx = probs + M;

  feat_kernel<<<M, 256, 0, stream>>>(x_m, x_op, job_srpt, m_ids, op_idx,
                                     job_ids, feat, srow);
  wconv_kernel<<<dim3(32, 16), 256, 0, stream>>>(W0, Wt0, 2048);
  wconv_kernel<<<dim3(16, 16), 256, 0, stream>>>(W1, Wt1, 1024);
  wconv_kernel<<<dim3(16, 16), 256, 0, stream>>>(W2, Wt2, 1024);
  hipMemsetAsync(score, 0, (size_t)M * 4, stream);

  // grid = (cols, rows): col index fast -> with xcd = bid%8 round-robin, each
  // XCD serves one B column-panel (L2-resident).
  gemm_kernel<<<dim3(4, 128), 512, 0, stream>>>(
      feat, Wt0, hA, b0, M, 1024, 2048, 1, W0 + (size_t)2048 * 1024,
      W0 + (size_t)2049 * 1024, srow, pt, 0, nullptr, nullptr);
  gemm_kernel<<<dim3(4, 128), 512, 0, stream>>>(hA, Wt1, hB, b1, M, 1024, 1024,
                                                0, nullptr, nullptr, nullptr,
                                                nullptr, 0, nullptr, nullptr);
  gemm_kernel<<<dim3(4, 128), 512, 0, stream>>>(hB, Wt2, nullptr, b2, M, 1024,
                                                1024, 0, nullptr, nullptr,
                                                nullptr, nullptr, 1, W3, score);

  redmax_kernel<<<64, 256, 0, stream>>>(score, pmax, pidx);
  finmax_kernel<<<1, 64, 0, stream>>>(pmax, pidx, gscal, out_idx);
  expsum_kernel<<<64, 256, 0, stream>>>(score, gscal, probs, psum);
  finsum_kernel<<<1, 64, 0, stream>>>(psum, gscal);
  scale_kernel<<<64, 256, 0, stream>>>(probs, gscal);
}